// Round 17
// baseline (500.566 us; speedup 1.0000x reference)
//
#include <hip/hip_runtime.h>

#define DIN 128      // D_IN == N_HEADS*D_HEAD == 128
#define NHEADS 8
#define DHEAD 16
#define NPB 32       // nodes per block (node_proj)
#define EPB 256      // edges per block (edge mfma kernel: 4 waves x 4 chunks x 16)

typedef __attribute__((ext_vector_type(8))) short short8;   // 8 bf16 (4 VGPRs)
typedef __attribute__((ext_vector_type(4))) float f32x4;    // MFMA C/D + NT ld/st

__device__ __forceinline__ float clip5(float x) {
    return fminf(fmaxf(x, -5.0f), 5.0f);
}

__device__ __forceinline__ unsigned short f2bf(float f) {   // RNE f32->bf16
    unsigned u = __float_as_uint(f);
    unsigned r = (u + 0x7FFF + ((u >> 16) & 1)) >> 16;
    return (unsigned short)r;
}

__device__ __forceinline__ float b2f(unsigned short u) {    // bf16 -> f32
    return __uint_as_float((unsigned)u << 16);
}

__device__ __forceinline__ float bflo(unsigned u) {  // low bf16 of dword
    return __uint_as_float(u << 16);
}
__device__ __forceinline__ float bfhi(unsigned u) {  // high bf16 of dword
    return __uint_as_float(u & 0xffff0000u);
}

// ---------------- node projections (fp32 VALU, bf16 stores) ----------------

__device__ __forceinline__ void tile_gemm(const float xs[][DIN], int r0, int cg,
                                          const float* __restrict__ W,
                                          float4 acc[4]) {
#pragma unroll 4
    for (int kk = 0; kk < DIN; kk += 4) {
        float4 a[4];
#pragma unroll
        for (int i = 0; i < 4; ++i)
            a[i] = *(const float4*)&xs[r0 + i][kk];
#pragma unroll
        for (int t = 0; t < 4; ++t) {
            float4 w = *(const float4*)&W[(kk + t) * DIN + (cg << 2)];
#pragma unroll
            for (int i = 0; i < 4; ++i) {
                float av = ((const float*)&a[i])[t];
                acc[i].x = fmaf(av, w.x, acc[i].x);
                acc[i].y = fmaf(av, w.y, acc[i].y);
                acc[i].z = fmaf(av, w.z, acc[i].z);
                acc[i].w = fmaf(av, w.w, acc[i].w);
            }
        }
    }
}

__global__ __launch_bounds__(256) void node_proj_kernel(
    const float* __restrict__ x, const float* __restrict__ WQ,
    const float* __restrict__ WK, const float* __restrict__ WV,
    unsigned short* __restrict__ qbf, unsigned short* __restrict__ kbf,
    unsigned short* __restrict__ vbf, int N) {
    __shared__ float xs[NPB][DIN];
    const int tid = threadIdx.x;
    const int n0 = blockIdx.x * NPB;

#pragma unroll
    for (int i = 0; i < NPB * DIN / (256 * 4); ++i) {
        int idx = (tid + i * 256) * 4;
        int r = idx / DIN, c = idx % DIN;
        float4 val = make_float4(0.f, 0.f, 0.f, 0.f);
        if (n0 + r < N) val = *(const float4*)&x[(long)(n0 + r) * DIN + c];
        *(float4*)&xs[r][c] = val;
    }
    __syncthreads();

    const int cg = tid & 31;
    const int ng = tid >> 5;
    const int r0 = ng * 4;

    const float* Ws[3] = {WQ, WK, WV};
    unsigned short* outs[3] = {qbf, kbf, vbf};
#pragma unroll
    for (int m = 0; m < 3; ++m) {
        float4 acc[4] = {make_float4(0,0,0,0), make_float4(0,0,0,0),
                         make_float4(0,0,0,0), make_float4(0,0,0,0)};
        tile_gemm(xs, r0, cg, Ws[m], acc);
#pragma unroll
        for (int i = 0; i < 4; ++i) {
            int n = n0 + r0 + i;
            if (n < N) {
                ushort4 b;
                b.x = f2bf(acc[i].x); b.y = f2bf(acc[i].y);
                b.z = f2bf(acc[i].z); b.w = f2bf(acc[i].w);
                *(ushort4*)&outs[m][(long)n * DIN + (cg << 2)] = b;
            }
        }
    }
}

// ---------------- CSR build (counting sort by destination col) ----------------

__global__ __launch_bounds__(256) void degree_kernel(
    const int* __restrict__ cols, int* __restrict__ deg, int E) {
    int e = blockIdx.x * 256 + threadIdx.x;
    if (e < E) atomicAdd(&deg[cols[e]], 1);
}

__global__ __launch_bounds__(256) void block_sum_kernel(
    const int* __restrict__ deg, int* __restrict__ bsum, int N) {
    __shared__ int s[256];
    int tid = threadIdx.x;
    int i = blockIdx.x * 256 + tid;
    s[tid] = (i < N) ? deg[i] : 0;
    __syncthreads();
    for (int st = 128; st > 0; st >>= 1) {
        if (tid < st) s[tid] += s[tid + st];
        __syncthreads();
    }
    if (tid == 0) bsum[blockIdx.x] = s[0];
}

__global__ __launch_bounds__(256) void scan_bsum_kernel(int* __restrict__ bsum, int NB) {
    __shared__ int s[256];
    int tid = threadIdx.x;
    int v = (tid < NB) ? bsum[tid] : 0;
    s[tid] = v;
    __syncthreads();
    for (int off = 1; off < 256; off <<= 1) {
        int t = (tid >= off) ? s[tid - off] : 0;
        __syncthreads();
        s[tid] += t;
        __syncthreads();
    }
    if (tid < NB) bsum[tid] = s[tid] - v;   // exclusive
}

__global__ __launch_bounds__(256) void offsets_kernel(
    const int* __restrict__ deg, const int* __restrict__ bsumscan,
    int* __restrict__ offsets, int* __restrict__ cursor, int N, int E) {
    __shared__ int s[256];
    int tid = threadIdx.x;
    int i = blockIdx.x * 256 + tid;
    int v = (i < N) ? deg[i] : 0;
    s[tid] = v;
    __syncthreads();
    for (int off = 1; off < 256; off <<= 1) {
        int t = (tid >= off) ? s[tid - off] : 0;
        __syncthreads();
        s[tid] += t;
        __syncthreads();
    }
    int excl = s[tid] - v + bsumscan[blockIdx.x];
    if (i < N) { offsets[i] = excl; cursor[i] = excl; }
    if (blockIdx.x == 0 && tid == 0) offsets[N] = E;
}

// scatter also materializes sorted endpoint arrays: rows_s/cols_s[j] for
// j in elist order -> downstream kernels read them contiguously.
__global__ __launch_bounds__(256) void scatter_kernel(
    const int* __restrict__ rows, const int* __restrict__ cols,
    int* __restrict__ cursor, int* __restrict__ elist,
    int* __restrict__ rows_s, int* __restrict__ cols_s, int E) {
    int e = blockIdx.x * 256 + threadIdx.x;
    if (e >= E) return;
    int c = cols[e];
    int pos = atomicAdd(&cursor[c], 1);
    elist[pos] = e;
    rows_s[pos] = rows[e];
    cols_s[pos] = c;
}

// ---------------- WE -> bf16 transposed [n][k] ----------------

__global__ __launch_bounds__(256) void prep_wet_kernel(
    const float* __restrict__ WE, unsigned short* __restrict__ WEt) {
    int idx = blockIdx.x * 256 + threadIdx.x;    // 16384 total
    int kk = idx >> 7, n = idx & 127;
    WEt[n * DIN + kk] = f2bf(WE[kk * DIN + n]);
}

// ---------------- edge compute: register-pipelined MFMA ----------------
// 4 waves/block, each wave owns 64 sorted slots processed as 4 chunks of 16.
// 2-stage register pipeline: indices prefetched 2 chunks ahead, data (8 ea
// NT loads + 16 k/q gathers, ~64 VGPR) double-buffered 1 chunk ahead.
// Compute of chunk c overlaps chunk c+1's loads -> 2x outstanding bytes per
// SIMD vs R13 (the R7-R13 invariant ~284us was Little's-law-bound).

__global__ __launch_bounds__(256, 2) void edge_mfma_kernel(
    const float* __restrict__ edge_attr, const int* __restrict__ elist,
    const int* __restrict__ rows_s, const int* __restrict__ cols_s,
    const unsigned short* __restrict__ WEt, const unsigned short* __restrict__ qbf,
    const unsigned short* __restrict__ kbf, float* __restrict__ e_out,
    float* __restrict__ ax_s, int E) {
    const int tid = threadIdx.x;
    const int e0 = blockIdx.x * EPB;
    const int w = tid >> 6;
    const int l = tid & 63;
    const int lr = l & 15;
    const int lg = l >> 4;
    const int jbase = e0 + w * 64;   // wave's 64 sorted slots

    bool valid[4];
    int eg_[4], er_[4], ec_[4];
    f32x4 ea_[2][8];
    ushort4 kv_[2][8], qv_[2][8];

#pragma unroll
    for (int c = 0; c < 4; ++c) valid[c] = (jbase + c * 16) < E;

#define IDX_LOAD(c)                                                  \
    if (valid[c]) {                                                  \
        int j = jbase + (c) * 16 + lr;                               \
        eg_[c] = elist[j]; er_[c] = rows_s[j]; ec_[c] = cols_s[j];   \
    }

#define DATA_LOAD(s, c)                                              \
    if (valid[c]) {                                                  \
        const float* arow = &edge_attr[(long)eg_[c] * DIN + lg * 8]; \
        _Pragma("unroll")                                            \
        for (int ks = 0; ks < 4; ++ks) {                             \
            ea_[s][ks * 2]     = __builtin_nontemporal_load((const f32x4*)&arow[ks * 32]);     \
            ea_[s][ks * 2 + 1] = __builtin_nontemporal_load((const f32x4*)&arow[ks * 32 + 4]); \
        }                                                            \
        const unsigned short* krow = &kbf[(long)er_[c] * DIN + lg * 4]; \
        const unsigned short* qrow = &qbf[(long)ec_[c] * DIN + lg * 4]; \
        _Pragma("unroll")                                            \
        for (int ft = 0; ft < 8; ++ft) {                             \
            kv_[s][ft] = *(const ushort4*)&krow[ft * 16];            \
            qv_[s][ft] = *(const ushort4*)&qrow[ft * 16];            \
        }                                                            \
    }

    // prologue: indices for chunks 0,1; data for chunk 0
    IDX_LOAD(0)
    IDX_LOAD(1)
    __builtin_amdgcn_sched_barrier(0);
    DATA_LOAD(0, 0)
    __builtin_amdgcn_sched_barrier(0);

#pragma unroll
    for (int c = 0; c < 4; ++c) {
        const int s = c & 1;
        // issue next-next indices and next data before computing current
        if (c + 2 < 4) { IDX_LOAD(c + 2) }
        if (c + 1 < 4) { DATA_LOAD((c + 1) & 1, c + 1) }
        __builtin_amdgcn_sched_barrier(0);

        if (valid[c]) {
            const int j = jbase + c * 16 + lr;
            const long eg = eg_[c];

            short8 bfrag[4];
#pragma unroll
            for (int ks = 0; ks < 4; ++ks) {
                f32x4 a0 = ea_[s][ks * 2], a1 = ea_[s][ks * 2 + 1];
                short8 f;
                f[0] = (short)f2bf(a0[0]); f[1] = (short)f2bf(a0[1]);
                f[2] = (short)f2bf(a0[2]); f[3] = (short)f2bf(a0[3]);
                f[4] = (short)f2bf(a1[0]); f[5] = (short)f2bf(a1[1]);
                f[6] = (short)f2bf(a1[2]); f[7] = (short)f2bf(a1[3]);
                bfrag[ks] = f;
            }

#pragma unroll
            for (int ft = 0; ft < 8; ++ft) {             // ft == head
                f32x4 acc = (f32x4){0.f, 0.f, 0.f, 0.f};
#pragma unroll
                for (int ks = 0; ks < 4; ++ks) {
                    short8 af = *(const short8*)&WEt[(ft * 16 + lr) * DIN + ks * 32 + lg * 8];
                    acc = __builtin_amdgcn_mfma_f32_16x16x32_bf16(af, bfrag[ks], acc, 0, 0, 0);
                }
                const int f0 = ft * 16 + lg * 4;
                f32x4 t;
                t[0] = clip5(b2f(kv_[s][ft].x) * b2f(qv_[s][ft].x) * 0.25f) * acc[0];
                t[1] = clip5(b2f(kv_[s][ft].y) * b2f(qv_[s][ft].y) * 0.25f) * acc[1];
                t[2] = clip5(b2f(kv_[s][ft].z) * b2f(qv_[s][ft].z) * 0.25f) * acc[2];
                t[3] = clip5(b2f(kv_[s][ft].w) * b2f(qv_[s][ft].w) * 0.25f) * acc[3];
                __builtin_nontemporal_store(t, (f32x4*)&e_out[eg * DIN + f0]);

                float sum = t[0] + t[1] + t[2] + t[3];
                sum += __shfl_xor(sum, 16);
                sum += __shfl_xor(sum, 32);
                float axv = __expf(clip5(sum));
                if (lg == 0)
                    ax_s[(long)j * NHEADS + ft] = axv;
            }
        }
        __builtin_amdgcn_sched_barrier(0);
    }
#undef IDX_LOAD
#undef DATA_LOAD
}

// ---------------- per-node gather aggregation (no atomics) ----------------

__global__ __launch_bounds__(256) void aggregate_kernel(
    const int* __restrict__ offsets, const int* __restrict__ rows_s,
    const float* __restrict__ ax_s, const unsigned short* __restrict__ vbf,
    float* __restrict__ h_out, int N) {
    int wid = blockIdx.x * 4 + (threadIdx.x >> 6);   // one wave per node
    int lane = threadIdx.x & 63;
    if (wid >= N) return;
    int beg = offsets[wid], end = offsets[wid + 1];
    const int head = lane >> 3;

    float2 acc = make_float2(0.f, 0.f);
    float zacc = 0.f;

    for (int j = beg; j < end; j += 8) {
        int n = end - j; n = (n > 8) ? 8 : n;
        int r_[8]; float a_[8]; unsigned u_[8];
#pragma unroll
        for (int t = 0; t < 8; ++t)
            r_[t] = rows_s[j + ((t < n) ? t : 0)];        // contiguous
#pragma unroll
        for (int t = 0; t < 8; ++t) {
            a_[t] = (t < n) ? ax_s[(long)(j + t) * NHEADS + head] : 0.f;  // contiguous
            u_[t] = *(const unsigned*)&vbf[(long)r_[t] * DIN + lane * 2]; // gather
        }
#pragma unroll
        for (int t = 0; t < 8; ++t) {
            acc.x = fmaf(bflo(u_[t]), a_[t], acc.x);
            acc.y = fmaf(bfhi(u_[t]), a_[t], acc.y);
            zacc += a_[t];
        }
    }
    float inv = 1.0f / (zacc + 1e-6f);
    float2 res = make_float2(acc.x * inv, acc.y * inv);
    *(float2*)&h_out[(long)wid * DIN + lane * 2] = res;
}

extern "C" void kernel_launch(void* const* d_in, const int* in_sizes, int n_in,
                              void* d_out, int out_size, void* d_ws, size_t ws_size,
                              hipStream_t stream) {
    const float* x         = (const float*)d_in[0];
    const float* edge_attr = (const float*)d_in[1];
    const int*   edge_index= (const int*)d_in[2];
    const float* WQ        = (const float*)d_in[3];
    const float* WK        = (const float*)d_in[4];
    const float* WV        = (const float*)d_in[5];
    const float* WE        = (const float*)d_in[6];

    const int N = in_sizes[0] / DIN;     // 50000
    const int E = in_sizes[2] / 2;       // 600000 (multiple of 64)
    const int NB = (N + 255) / 256;

    float* out   = (float*)d_out;
    float* h_out = out;                        // [N,128]
    float* e_out = out + (long)N * DIN;        // [E,128]

    unsigned short* qbf = (unsigned short*)d_ws;            // [N,128] bf16
    unsigned short* kbf = qbf + (long)N * DIN;              // [N,128] bf16
    unsigned short* vbf = kbf + (long)N * DIN;              // [N,128] bf16
    float* ax_s = (float*)(vbf + (long)N * DIN);            // [E,8] sorted order
    unsigned short* WEt = (unsigned short*)(ax_s + (long)E * NHEADS);  // [128,128] bf16
    int* ip      = (int*)(WEt + DIN * DIN);
    int* deg     = ip;                         // [N]
    int* cursor  = deg + N;                    // [N]
    int* offsets = cursor + N;                 // [N+1]
    int* bsum    = offsets + N + 1;            // [NB]
    int* elist   = bsum + 256;                 // [E]
    int* rows_s  = elist + E;                  // [E]
    int* cols_s  = rows_s + E;                 // [E]

    const int* rows = edge_index;
    const int* cols = edge_index + E;

    hipMemsetAsync(deg, 0, (size_t)N * sizeof(int), stream);

    node_proj_kernel<<<(N + NPB - 1) / NPB, 256, 0, stream>>>(x, WQ, WK, WV, qbf, kbf, vbf, N);
    prep_wet_kernel<<<DIN * DIN / 256, 256, 0, stream>>>(WE, WEt);

    degree_kernel<<<(E + 255) / 256, 256, 0, stream>>>(cols, deg, E);
    block_sum_kernel<<<NB, 256, 0, stream>>>(deg, bsum, N);
    scan_bsum_kernel<<<1, 256, 0, stream>>>(bsum, NB);
    offsets_kernel<<<NB, 256, 0, stream>>>(deg, bsum, offsets, cursor, N, E);
    scatter_kernel<<<(E + 255) / 256, 256, 0, stream>>>(rows, cols, cursor,
                                                        elist, rows_s, cols_s, E);

    edge_mfma_kernel<<<(E + EPB - 1) / EPB, 256, 0, stream>>>(
        edge_attr, elist, rows_s, cols_s, WEt, qbf, kbf, e_out, ax_s, E);

    aggregate_kernel<<<(N + 3) / 4, 256, 0, stream>>>(
        offsets, rows_s, ax_s, vbf, h_out, N);
}

// Round 18
// 484.099 us; speedup vs baseline: 1.0340x; 1.0340x over previous
//
#include <hip/hip_runtime.h>

#define DIN 128      // D_IN == N_HEADS*D_HEAD == 128
#define NHEADS 8
#define DHEAD 16
#define NPB 32       // nodes per block (node_proj)
#define EPB 64       // edges per block (edge mfma kernel)

typedef __attribute__((ext_vector_type(8))) short short8;   // 8 bf16 (4 VGPRs)
typedef __attribute__((ext_vector_type(4))) float f32x4;    // MFMA C/D + NT ld/st

__device__ __forceinline__ float clip5(float x) {
    return fminf(fmaxf(x, -5.0f), 5.0f);
}

__device__ __forceinline__ unsigned short f2bf(float f) {   // RNE f32->bf16
    unsigned u = __float_as_uint(f);
    unsigned r = (u + 0x7FFF + ((u >> 16) & 1)) >> 16;
    return (unsigned short)r;
}

__device__ __forceinline__ float b2f(unsigned short u) {    // bf16 -> f32
    return __uint_as_float((unsigned)u << 16);
}

__device__ __forceinline__ float bflo(unsigned u) {  // low bf16 of dword
    return __uint_as_float(u << 16);
}
__device__ __forceinline__ float bfhi(unsigned u) {  // high bf16 of dword
    return __uint_as_float(u & 0xffff0000u);
}

// ---------------- node projections (fp32 VALU, bf16 stores) ----------------

__device__ __forceinline__ void tile_gemm(const float xs[][DIN], int r0, int cg,
                                          const float* __restrict__ W,
                                          float4 acc[4]) {
#pragma unroll 4
    for (int kk = 0; kk < DIN; kk += 4) {
        float4 a[4];
#pragma unroll
        for (int i = 0; i < 4; ++i)
            a[i] = *(const float4*)&xs[r0 + i][kk];
#pragma unroll
        for (int t = 0; t < 4; ++t) {
            float4 w = *(const float4*)&W[(kk + t) * DIN + (cg << 2)];
#pragma unroll
            for (int i = 0; i < 4; ++i) {
                float av = ((const float*)&a[i])[t];
                acc[i].x = fmaf(av, w.x, acc[i].x);
                acc[i].y = fmaf(av, w.y, acc[i].y);
                acc[i].z = fmaf(av, w.z, acc[i].z);
                acc[i].w = fmaf(av, w.w, acc[i].w);
            }
        }
    }
}

__global__ __launch_bounds__(256) void node_proj_kernel(
    const float* __restrict__ x, const float* __restrict__ WQ,
    const float* __restrict__ WK, const float* __restrict__ WV,
    unsigned short* __restrict__ qbf, unsigned short* __restrict__ kbf,
    unsigned short* __restrict__ vbf, int N) {
    __shared__ float xs[NPB][DIN];
    const int tid = threadIdx.x;
    const int n0 = blockIdx.x * NPB;

#pragma unroll
    for (int i = 0; i < NPB * DIN / (256 * 4); ++i) {
        int idx = (tid + i * 256) * 4;
        int r = idx / DIN, c = idx % DIN;
        float4 val = make_float4(0.f, 0.f, 0.f, 0.f);
        if (n0 + r < N) val = *(const float4*)&x[(long)(n0 + r) * DIN + c];
        *(float4*)&xs[r][c] = val;
    }
    __syncthreads();

    const int cg = tid & 31;
    const int ng = tid >> 5;
    const int r0 = ng * 4;

    const float* Ws[3] = {WQ, WK, WV};
    unsigned short* outs[3] = {qbf, kbf, vbf};
#pragma unroll
    for (int m = 0; m < 3; ++m) {
        float4 acc[4] = {make_float4(0,0,0,0), make_float4(0,0,0,0),
                         make_float4(0,0,0,0), make_float4(0,0,0,0)};
        tile_gemm(xs, r0, cg, Ws[m], acc);
#pragma unroll
        for (int i = 0; i < 4; ++i) {
            int n = n0 + r0 + i;
            if (n < N) {
                ushort4 b;
                b.x = f2bf(acc[i].x); b.y = f2bf(acc[i].y);
                b.z = f2bf(acc[i].z); b.w = f2bf(acc[i].w);
                *(ushort4*)&outs[m][(long)n * DIN + (cg << 2)] = b;
            }
        }
    }
}

// ---------------- CSR build (counting sort by destination col) ----------------

__global__ __launch_bounds__(256) void degree_kernel(
    const int* __restrict__ cols, int* __restrict__ deg, int E) {
    int e = blockIdx.x * 256 + threadIdx.x;
    if (e < E) atomicAdd(&deg[cols[e]], 1);
}

__global__ __launch_bounds__(256) void block_sum_kernel(
    const int* __restrict__ deg, int* __restrict__ bsum, int N) {
    __shared__ int s[256];
    int tid = threadIdx.x;
    int i = blockIdx.x * 256 + tid;
    s[tid] = (i < N) ? deg[i] : 0;
    __syncthreads();
    for (int st = 128; st > 0; st >>= 1) {
        if (tid < st) s[tid] += s[tid + st];
        __syncthreads();
    }
    if (tid == 0) bsum[blockIdx.x] = s[0];
}

__global__ __launch_bounds__(256) void scan_bsum_kernel(int* __restrict__ bsum, int NB) {
    __shared__ int s[256];
    int tid = threadIdx.x;
    int v = (tid < NB) ? bsum[tid] : 0;
    s[tid] = v;
    __syncthreads();
    for (int off = 1; off < 256; off <<= 1) {
        int t = (tid >= off) ? s[tid - off] : 0;
        __syncthreads();
        s[tid] += t;
        __syncthreads();
    }
    if (tid < NB) bsum[tid] = s[tid] - v;   // exclusive
}

__global__ __launch_bounds__(256) void offsets_kernel(
    const int* __restrict__ deg, const int* __restrict__ bsumscan,
    int* __restrict__ offsets, int* __restrict__ cursor, int N, int E) {
    __shared__ int s[256];
    int tid = threadIdx.x;
    int i = blockIdx.x * 256 + tid;
    int v = (i < N) ? deg[i] : 0;
    s[tid] = v;
    __syncthreads();
    for (int off = 1; off < 256; off <<= 1) {
        int t = (tid >= off) ? s[tid - off] : 0;
        __syncthreads();
        s[tid] += t;
        __syncthreads();
    }
    int excl = s[tid] - v + bsumscan[blockIdx.x];
    if (i < N) { offsets[i] = excl; cursor[i] = excl; }
    if (blockIdx.x == 0 && tid == 0) offsets[N] = E;
}

// scatter also materializes sorted endpoint arrays: rows_s/cols_s[j] for
// j in elist order -> downstream kernels read them contiguously.
__global__ __launch_bounds__(256) void scatter_kernel(
    const int* __restrict__ rows, const int* __restrict__ cols,
    int* __restrict__ cursor, int* __restrict__ elist,
    int* __restrict__ rows_s, int* __restrict__ cols_s, int E) {
    int e = blockIdx.x * 256 + threadIdx.x;
    if (e >= E) return;
    int c = cols[e];
    int pos = atomicAdd(&cursor[c], 1);
    elist[pos] = e;
    rows_s[pos] = rows[e];
    cols_s[pos] = c;
}

// ---------------- WE -> bf16 transposed [n][k] ----------------

__global__ __launch_bounds__(256) void prep_wet_kernel(
    const float* __restrict__ WE, unsigned short* __restrict__ WEt) {
    int idx = blockIdx.x * 256 + threadIdx.x;    // 16384 total
    int kk = idx >> 7, n = idx & 127;
    WEt[n * DIN + kk] = f2bf(WE[kk * DIN + n]);
}

// ---------------- edge compute: MFMA e_proj + e_out + ax_s ----------------
// R13 form (best measured: 285us, VGPR 52). Sorted order, burst loads,
// nontemporal one-touch streams. R17 proved deeper per-wave pipelining
// trades occupancy 1:1 -> reverted.

__global__ __launch_bounds__(256) void edge_mfma_kernel(
    const float* __restrict__ edge_attr, const int* __restrict__ elist,
    const int* __restrict__ rows_s, const int* __restrict__ cols_s,
    const unsigned short* __restrict__ WEt, const unsigned short* __restrict__ qbf,
    const unsigned short* __restrict__ kbf, float* __restrict__ e_out,
    float* __restrict__ ax_s, int E) {
    const int tid = threadIdx.x;
    const int e0 = blockIdx.x * EPB;              // E % EPB == 0
    const int w = tid >> 6;          // wave 0..3: sorted slots w*16..w*16+15
    const int l = tid & 63;
    const int lr = l & 15;
    const int lg = l >> 4;
    const int j = e0 + w * 16 + lr;  // sorted position
    const long eg = elist[j];        // original edge id (row gather target)
    const int er = rows_s[j];        // contiguous
    const int ec = cols_s[j];        // contiguous, sorted (locality!)

    // ---- burst 1: 8 edge_attr f32x4 loads (own row, nontemporal) ----
    const float* arow = &edge_attr[eg * DIN + lg * 8];
    f32x4 ea[8];
#pragma unroll
    for (int ks = 0; ks < 4; ++ks) {
        ea[ks * 2]     = __builtin_nontemporal_load((const f32x4*)&arow[ks * 32]);
        ea[ks * 2 + 1] = __builtin_nontemporal_load((const f32x4*)&arow[ks * 32 + 4]);
    }
    // ---- burst 2: 16 k/q ushort4 gathers ----
    const unsigned short* krow = &kbf[(long)er * DIN + lg * 4];
    const unsigned short* qrow = &qbf[(long)ec * DIN + lg * 4];
    ushort4 kv[8], qv[8];
#pragma unroll
    for (int ft = 0; ft < 8; ++ft) {
        kv[ft] = *(const ushort4*)&krow[ft * 16];
        qv[ft] = *(const ushort4*)&qrow[ft * 16];
    }
    __builtin_amdgcn_sched_barrier(0);   // loads stay a burst

    // convert edge_attr -> bf16 B-fragments (k-window = ks*32 + lg*8)
    short8 bfrag[4];
#pragma unroll
    for (int ks = 0; ks < 4; ++ks) {
        f32x4 a0 = ea[ks * 2], a1 = ea[ks * 2 + 1];
        short8 f;
        f[0] = (short)f2bf(a0[0]); f[1] = (short)f2bf(a0[1]);
        f[2] = (short)f2bf(a0[2]); f[3] = (short)f2bf(a0[3]);
        f[4] = (short)f2bf(a1[0]); f[5] = (short)f2bf(a1[1]);
        f[6] = (short)f2bf(a1[2]); f[7] = (short)f2bf(a1[3]);
        bfrag[ks] = f;
    }

#pragma unroll
    for (int ft = 0; ft < 8; ++ft) {             // ft == head
        f32x4 acc = (f32x4){0.f, 0.f, 0.f, 0.f};
#pragma unroll
        for (int ks = 0; ks < 4; ++ks) {
            short8 af = *(const short8*)&WEt[(ft * 16 + lr) * DIN + ks * 32 + lg * 8];
            acc = __builtin_amdgcn_mfma_f32_16x16x32_bf16(af, bfrag[ks], acc, 0, 0, 0);
        }
        const int f0 = ft * 16 + lg * 4;         // 4 consecutive features
        f32x4 t;
        t[0] = clip5(b2f(kv[ft].x) * b2f(qv[ft].x) * 0.25f) * acc[0];
        t[1] = clip5(b2f(kv[ft].y) * b2f(qv[ft].y) * 0.25f) * acc[1];
        t[2] = clip5(b2f(kv[ft].z) * b2f(qv[ft].z) * 0.25f) * acc[2];
        t[3] = clip5(b2f(kv[ft].w) * b2f(qv[ft].w) * 0.25f) * acc[3];
        __builtin_nontemporal_store(t, (f32x4*)&e_out[eg * DIN + f0]);

        float s = t[0] + t[1] + t[2] + t[3];     // this lane's 4-feature partial
        s += __shfl_xor(s, 16);                  // reduce over lg groups
        s += __shfl_xor(s, 32);
        float axv = __expf(clip5(s));
        if (lg == 0)
            ax_s[(long)j * NHEADS + ft] = axv;   // contiguous in sorted order
    }
}

// ---------------- per-node gather aggregation (no atomics) ----------------
// One wave per node. Lane = (sub = lane>>4, f16 = lane&15): each 16-lane
// group handles one edge, each lane loads 16B of v (8 bf16 features).
// 8 edges per iteration (2 groups of 4), cross-sub shfl reduce at the end.
// vs R13: same bytes, ~3x fewer memory instructions, 16B loads not 4B.

__global__ __launch_bounds__(256) void aggregate_kernel(
    const int* __restrict__ offsets, const int* __restrict__ rows_s,
    const float* __restrict__ ax_s, const unsigned short* __restrict__ vbf,
    float* __restrict__ h_out, int N) {
    int wid = blockIdx.x * 4 + (threadIdx.x >> 6);   // one wave per node
    int lane = threadIdx.x & 63;
    if (wid >= N) return;
    int beg = offsets[wid], end = offsets[wid + 1];
    const int sub = lane >> 4;       // edge within group of 4
    const int f16 = lane & 15;       // features f16*8 .. f16*8+7
    const int head = f16 >> 1;

    if (beg == end) {                // isolated node: z=0 -> h=0
        if (sub == 0) {
            f32x4 zz = (f32x4){0.f, 0.f, 0.f, 0.f};
            *(f32x4*)&h_out[(long)wid * DIN + f16 * 8] = zz;
            *(f32x4*)&h_out[(long)wid * DIN + f16 * 8 + 4] = zz;
        }
        return;
    }

    float acc[8] = {0.f, 0.f, 0.f, 0.f, 0.f, 0.f, 0.f, 0.f};
    float zacc = 0.f;

    for (int j = beg; j < end; j += 8) {
        int n = end - j;
        bool v0 = sub < n, v1 = 4 + sub < n;
        int jj0 = v0 ? (j + sub) : beg;
        int jj1 = v1 ? (j + 4 + sub) : beg;
        int r0 = rows_s[jj0], r1 = rows_s[jj1];
        float a0 = v0 ? ax_s[(long)jj0 * NHEADS + head] : 0.f;
        float a1 = v1 ? ax_s[(long)jj1 * NHEADS + head] : 0.f;
        uint4 u0 = *(const uint4*)&vbf[(long)r0 * DIN + f16 * 8];
        uint4 u1 = *(const uint4*)&vbf[(long)r1 * DIN + f16 * 8];

        acc[0] = fmaf(bflo(u0.x), a0, acc[0]); acc[1] = fmaf(bfhi(u0.x), a0, acc[1]);
        acc[2] = fmaf(bflo(u0.y), a0, acc[2]); acc[3] = fmaf(bfhi(u0.y), a0, acc[3]);
        acc[4] = fmaf(bflo(u0.z), a0, acc[4]); acc[5] = fmaf(bfhi(u0.z), a0, acc[5]);
        acc[6] = fmaf(bflo(u0.w), a0, acc[6]); acc[7] = fmaf(bfhi(u0.w), a0, acc[7]);
        zacc += a0;
        acc[0] = fmaf(bflo(u1.x), a1, acc[0]); acc[1] = fmaf(bfhi(u1.x), a1, acc[1]);
        acc[2] = fmaf(bflo(u1.y), a1, acc[2]); acc[3] = fmaf(bfhi(u1.y), a1, acc[3]);
        acc[4] = fmaf(bflo(u1.z), a1, acc[4]); acc[5] = fmaf(bfhi(u1.z), a1, acc[5]);
        acc[6] = fmaf(bflo(u1.w), a1, acc[6]); acc[7] = fmaf(bfhi(u1.w), a1, acc[7]);
        zacc += a1;
    }

#pragma unroll
    for (int i = 0; i < 8; ++i) {
        acc[i] += __shfl_xor(acc[i], 16);
        acc[i] += __shfl_xor(acc[i], 32);
    }
    zacc += __shfl_xor(zacc, 16);
    zacc += __shfl_xor(zacc, 32);

    if (sub == 0) {
        float inv = 1.0f / (zacc + 1e-6f);
        f32x4 r0 = (f32x4){acc[0] * inv, acc[1] * inv, acc[2] * inv, acc[3] * inv};
        f32x4 r1 = (f32x4){acc[4] * inv, acc[5] * inv, acc[6] * inv, acc[7] * inv};
        *(f32x4*)&h_out[(long)wid * DIN + f16 * 8] = r0;
        *(f32x4*)&h_out[(long)wid * DIN + f16 * 8 + 4] = r1;
    }
}

extern "C" void kernel_launch(void* const* d_in, const int* in_sizes, int n_in,
                              void* d_out, int out_size, void* d_ws, size_t ws_size,
                              hipStream_t stream) {
    const float* x         = (const float*)d_in[0];
    const float* edge_attr = (const float*)d_in[1];
    const int*   edge_index= (const int*)d_in[2];
    const float* WQ        = (const float*)d_in[3];
    const float* WK        = (const float*)d_in[4];
    const float* WV        = (const float*)d_in[5];
    const float* WE        = (const float*)d_in[6];

    const int N = in_sizes[0] / DIN;     // 50000
    const int E = in_sizes[2] / 2;       // 600000 (multiple of 64)
    const int NB = (N + 255) / 256;

    float* out   = (float*)d_out;
    float* h_out = out;                        // [N,128]
    float* e_out = out + (long)N * DIN;        // [E,128]

    unsigned short* qbf = (unsigned short*)d_ws;            // [N,128] bf16
    unsigned short* kbf = qbf + (long)N * DIN;              // [N,128] bf16
    unsigned short* vbf = kbf + (long)N * DIN;              // [N,128] bf16
    float* ax_s = (float*)(vbf + (long)N * DIN);            // [E,8] sorted order
    unsigned short* WEt = (unsigned short*)(ax_s + (long)E * NHEADS);  // [128,128] bf16
    int* ip      = (int*)(WEt + DIN * DIN);
    int* deg     = ip;                         // [N]
    int* cursor  = deg + N;                    // [N]
    int* offsets = cursor + N;                 // [N+1]
    int* bsum    = offsets + N + 1;            // [NB]
    int* elist   = bsum + 256;                 // [E]
    int* rows_s  = elist + E;                  // [E]
    int* cols_s  = rows_s + E;                 // [E]

    const int* rows = edge_index;
    const int* cols = edge_index + E;

    hipMemsetAsync(deg, 0, (size_t)N * sizeof(int), stream);

    node_proj_kernel<<<(N + NPB - 1) / NPB, 256, 0, stream>>>(x, WQ, WK, WV, qbf, kbf, vbf, N);
    prep_wet_kernel<<<DIN * DIN / 256, 256, 0, stream>>>(WE, WEt);

    degree_kernel<<<(E + 255) / 256, 256, 0, stream>>>(cols, deg, E);
    block_sum_kernel<<<NB, 256, 0, stream>>>(deg, bsum, N);
    scan_bsum_kernel<<<1, 256, 0, stream>>>(bsum, NB);
    offsets_kernel<<<NB, 256, 0, stream>>>(deg, bsum, offsets, cursor, N, E);
    scatter_kernel<<<(E + 255) / 256, 256, 0, stream>>>(rows, cols, cursor,
                                                        elist, rows_s, cols_s, E);

    edge_mfma_kernel<<<E / EPB, 256, 0, stream>>>(
        edge_attr, elist, rows_s, cols_s, WEt, qbf, kbf, e_out, ax_s, E);

    aggregate_kernel<<<(N + 3) / 4, 256, 0, stream>>>(
        offsets, rows_s, ax_s, vbf, h_out, N);
}